// Round 1
// baseline (13920.303 us; speedup 1.0000x reference)
//
#include <hip/hip_runtime.h>
#include <hip/hip_bf16.h>
#include <cstddef>

// Problem constants
#define BB    32
#define IMG   224
#define CIN   3
#define ED    64
#define TD    64
#define MM    32
#define HP    56
#define TT    3136      // 56*56
#define C4    256       // 4*ED
#define KQVN  192       // 3*TD

// workspace offsets (floats)
#define OFF_C1     0u           // 32*64*112*112 = 25,690,112   [conv1 out; dead after conv2]
#define OFF_CONVX  0u           // 32*3136*64    = 6,422,528    [after conv3]
#define OFF_KQV    6422528u     // 32*3136*192   = 19,267,584
#define OFF_C2     25690112u    // 32*64*56*56   = 6,422,528    [dead after conv3]
#define OFF_KP     25690112u    // 32*3136*32    = 3,211,264
#define OFF_QP     28901376u    // 32*3136*32    = 3,211,264
#define OFF_PART   32112640u    // 16*32*64*32   = 1,048,576
#define OFF_KPTV   33161216u    // 32*64*32      = 65,536
#define OFF_KPSUM  33226752u    // 32*32         = 1,024
// total = 33,227,776 floats = 132.9 MB

__device__ __forceinline__ float geluf(float v){
  return 0.5f*v*(1.f + erff(v*0.70710678118654752f));
}
__device__ __forceinline__ float siluf(float v){
  return v/(1.f + expf(-v));
}

// ---------------- conv1: x(32,3,224,224) -> c1(32,64,112,112), 3x3 s2 p1, SiLU
__global__ __launch_bounds__(256) void k_conv1(
    const float* __restrict__ x, const float* __restrict__ w,
    const float* __restrict__ bias, float* __restrict__ c1)
{
  const int oc = blockIdx.y, b = blockIdx.z;
  const int s = blockIdx.x*256 + threadIdx.x;   // 0..12543
  const int oh = s/112, ow = s - (s/112)*112;
  const float* wp = w + oc*27;
  const float* xb = x + (size_t)b*CIN*IMG*IMG;
  float acc = bias[oc];
  for (int ci=0; ci<3; ++ci){
    for (int kh=0; kh<3; ++kh){
      int ih = oh*2 - 1 + kh;
      if ((unsigned)ih >= (unsigned)IMG) continue;
      for (int kw=0; kw<3; ++kw){
        int iw = ow*2 - 1 + kw;
        if ((unsigned)iw >= (unsigned)IMG) continue;
        acc += wp[(ci*3+kh)*3+kw] * xb[(ci*IMG+ih)*IMG+iw];
      }
    }
  }
  c1[(((size_t)b*64+oc)*112+oh)*112+ow] = siluf(acc);
}

// ---------------- conv2: c1 -> c2(32,64,56,56), 3x3 s2 p1, BN+SiLU; 4 oc/thread
__global__ __launch_bounds__(256) void k_conv2(
    const float* __restrict__ c1, const float* __restrict__ w,
    const float* __restrict__ bias, const float* __restrict__ g,
    const float* __restrict__ bb, const float* __restrict__ mean,
    const float* __restrict__ var, float* __restrict__ c2)
{
  const int ocg = blockIdx.y, b = blockIdx.z;
  const int s = blockIdx.x*256 + threadIdx.x;
  if (s >= TT) return;
  const int oh = s/HP, ow = s - (s/HP)*HP;
  const int oc0 = ocg*4;
  float acc[4];
  #pragma unroll
  for (int u=0;u<4;++u) acc[u] = bias[oc0+u];
  const float* cb = c1 + (size_t)b*64*112*112;
  for (int ci=0; ci<64; ++ci){
    const float* xp = cb + ci*12544;
    const float* wq = w + ci*9;   // + oc*576
    for (int kh=0; kh<3; ++kh){
      int ih = oh*2 - 1 + kh;
      if ((unsigned)ih >= 112u) continue;
      for (int kw=0; kw<3; ++kw){
        int iw = ow*2 - 1 + kw;
        if ((unsigned)iw >= 112u) continue;
        float xv = xp[ih*112+iw];
        #pragma unroll
        for (int u=0;u<4;++u)
          acc[u] += wq[(oc0+u)*576 + kh*3+kw] * xv;
      }
    }
  }
  #pragma unroll
  for (int u=0;u<4;++u){
    int oc = oc0+u;
    float inv = g[oc]*rsqrtf(var[oc] + 1e-5f);
    float v = (acc[u] - mean[oc])*inv + bb[oc];
    c2[(((size_t)b*64+oc)*HP+oh)*HP+ow] = siluf(v);
  }
}

// ---------------- conv3: c2 -> convX(32,3136,64) NHWC, 3x3 s1 p1, SiLU
__global__ __launch_bounds__(256) void k_conv3(
    const float* __restrict__ c2, const float* __restrict__ w,
    const float* __restrict__ bias, float* __restrict__ convX)
{
  const int b = blockIdx.y;
  const int oc = threadIdx.x & 63, p = threadIdx.x >> 6;
  const int s = blockIdx.x*4 + p;
  const int oh = s/HP, ow = s - (s/HP)*HP;
  const float* cb = c2 + (size_t)b*64*TT;
  float acc = bias[oc];
  for (int ci=0; ci<64; ++ci){
    const float* xp = cb + ci*TT;
    const float* wq = w + (oc*64+ci)*9;
    for (int kh=0; kh<3; ++kh){
      int ih = oh - 1 + kh;
      if ((unsigned)ih >= (unsigned)HP) continue;
      for (int kw=0; kw<3; ++kw){
        int iw = ow - 1 + kw;
        if ((unsigned)iw >= (unsigned)HP) continue;
        acc += wq[kh*3+kw] * xp[ih*HP+iw];
      }
    }
  }
  convX[((size_t)b*TT + s)*64 + oc] = siluf(acc);
}

// ---------------- fused PRM convs + GELU + LN + KQV. one block = (oh, 14-wide ow strip)
__global__ __launch_bounds__(256) void k_prm_ln_kqv(
    const float* __restrict__ x, const float* __restrict__ prm_w,
    const float* __restrict__ prm_b, const float* __restrict__ ln_g,
    const float* __restrict__ ln_b, const float* __restrict__ kqv_w,
    const float* __restrict__ kqv_b, float* __restrict__ kqv)
{
  __shared__ __align__(16) float xt[3][25][80];
  __shared__ __align__(16) float xnsh[14][256];
  __shared__ float mu_s[14], rs_s[14];
  const int t = threadIdx.x;
  const int b = blockIdx.y;
  const int oh  = blockIdx.x >> 2;
  const int owt = blockIdx.x & 3;
  const int ow0 = owt*14;
  const int ih0 = oh*4 - 11;
  const int iw0 = ow0*4 - 11;

  // stage zero-padded x tile [3][25][80]
  const float* xb = x + (size_t)b*CIN*IMG*IMG;
  for (int idx = t; idx < 6000; idx += 256){
    int ci  = idx / 2000;
    int rem = idx - ci*2000;
    int r   = rem / 80;
    int cc  = rem - r*80;
    int ih = ih0 + r, iw = iw0 + cc;
    float val = 0.f;
    if ((unsigned)ih < (unsigned)IMG && (unsigned)iw < (unsigned)IMG)
      val = xb[(ci*IMG+ih)*IMG+iw];
    xt[ci][r][cc] = val;
  }
  __syncthreads();

  const int i = t >> 6, oc = t & 63;
  const int d = i + 1;
  const int r0 = 12 - 3*d;   // tile-relative base offset (pad = 3d-1)
  float v[14];
  const float bi = prm_b[i*64+oc];
  #pragma unroll
  for (int p=0;p<14;++p) v[p] = bi;
  const float* wp = prm_w + (i*64+oc)*147;

  for (int ci=0; ci<3; ++ci){
    for (int kh=0; kh<7; ++kh){
      const int rh = r0 + kh*d;
      const float* xrow = &xt[ci][rh][0];
      #pragma unroll
      for (int kw=0; kw<7; ++kw){
        const float wv = wp[(ci*7+kh)*7+kw];
        const int rw = r0 + kw*d;
        #pragma unroll
        for (int p=0;p<14;++p)
          v[p] += wv * xrow[p*4 + rw];
      }
    }
  }
  // GELU + stash for LN
  #pragma unroll
  for (int p=0;p<14;++p){
    float a = geluf(v[p]);
    v[p] = a;
    xnsh[p][t] = a;
  }
  __syncthreads();

  // LN stats: wave w handles p = w, w+4, ...
  const int wvid = t >> 6, lane = t & 63;
  for (int p = wvid; p < 14; p += 4){
    float s1 = 0.f, s2 = 0.f;
    for (int c = lane; c < 256; c += 64){
      float u = xnsh[p][c];
      s1 += u; s2 += u*u;
    }
    #pragma unroll
    for (int o=32;o;o>>=1){
      s1 += __shfl_down(s1, o, 64);
      s2 += __shfl_down(s2, o, 64);
    }
    if (lane == 0){
      float mu = s1*(1.f/256.f);
      float va = s2*(1.f/256.f) - mu*mu;
      mu_s[p] = mu;
      rs_s[p] = rsqrtf(va + 1e-5f);
    }
  }
  __syncthreads();
  const float lg = ln_g[t], lb = ln_b[t];
  #pragma unroll
  for (int p=0;p<14;++p)
    xnsh[p][t] = (v[p] - mu_s[p])*rs_s[p]*lg + lb;
  __syncthreads();

  // KQV: 14*192 = 2688 outputs
  const int s_base = oh*HP + ow0;
  for (int idx = t; idx < 2688; idx += 256){
    int p = idx / 192;
    int j = idx - p*192;
    const float4* wr = (const float4*)(kqv_w + j*256);
    const float4* xr = (const float4*)(&xnsh[p][0]);
    float acc = kqv_b[j];
    for (int c4=0;c4<64;++c4){
      float4 w4 = wr[c4];
      float4 xv = xr[c4];
      acc += xv.x*w4.x + xv.y*w4.y + xv.z*w4.z + xv.w*w4.w;
    }
    kqv[((size_t)b*TT + s_base + p)*KQVN + j] = acc;
  }
}

// ---------------- prm_exp: kqv -> kp (z.z=0) / qp (z.z=1)
__global__ __launch_bounds__(256) void k_prmexp(
    const float* __restrict__ kqv, const float* __restrict__ wperf,
    float* __restrict__ kp, float* __restrict__ qp)
{
  const int b = blockIdx.y;
  const int which = blockIdx.z;
  const int m = threadIdx.x & 31, pl = threadIdx.x >> 5;
  const int s = blockIdx.x*8 + pl;
  const float* z = kqv + ((size_t)b*TT + s)*KQVN + which*64;
  const float* wm = wperf + m*64;
  float xd = 0.f, wtx = 0.f;
  for (int i2=0;i2<64;i2+=4){
    float4 z4 = *(const float4*)(z+i2);
    float4 w4 = *(const float4*)(wm+i2);
    xd  += z4.x*z4.x + z4.y*z4.y + z4.z*z4.z + z4.w*z4.w;
    wtx += z4.x*w4.x + z4.y*w4.y + z4.z*w4.z + z4.w*w4.w;
  }
  float outv = expf(wtx - 0.5f*xd) * 0.17677669529663687f; // 1/sqrt(32)
  float* dst = which ? qp : kp;
  dst[((size_t)b*TT + s)*MM + m] = outv;
}

// ---------------- kpsum[b][m] = sum_t kp[b][t][m]
__global__ __launch_bounds__(256) void k_kpsum(
    const float* __restrict__ kp, float* __restrict__ kpsum)
{
  const int b = blockIdx.x;
  const int m = threadIdx.x & 31, g = threadIdx.x >> 5;
  __shared__ float part[8][32];
  float s = 0.f;
  for (int tt = g; tt < TT; tt += 8)
    s += kp[((size_t)b*TT + tt)*MM + m];
  part[g][m] = s;
  __syncthreads();
  if (threadIdx.x < 32){
    float a = 0.f;
    #pragma unroll
    for (int g2=0;g2<8;++g2) a += part[g2][threadIdx.x];
    kpsum[b*MM + threadIdx.x] = a;
  }
}

// ---------------- kptv partials: part[g][b][n][m] over t-range
__global__ __launch_bounds__(256) void k_kptv(
    const float* __restrict__ kqv, const float* __restrict__ kp,
    float* __restrict__ part)
{
  const int b = blockIdx.y, g = blockIdx.x;   // 16 groups of 196
  const int n = threadIdx.x & 63, mg = threadIdx.x >> 6; // mg: m-octet
  float acc[8] = {0,0,0,0,0,0,0,0};
  for (int tt = g*196; tt < (g+1)*196; ++tt){
    float vv = kqv[((size_t)b*TT + tt)*KQVN + 128 + n];
    const float4* kp4 = (const float4*)(kp + ((size_t)b*TT + tt)*MM + mg*8);
    float4 a0 = kp4[0], a1 = kp4[1];
    acc[0] += vv*a0.x; acc[1] += vv*a0.y; acc[2] += vv*a0.z; acc[3] += vv*a0.w;
    acc[4] += vv*a1.x; acc[5] += vv*a1.y; acc[6] += vv*a1.z; acc[7] += vv*a1.w;
  }
  #pragma unroll
  for (int j=0;j<8;++j)
    part[(((size_t)g*BB + b)*64 + n)*MM + mg*8 + j] = acc[j];
}

__global__ __launch_bounds__(256) void k_kptv_red(
    const float* __restrict__ part, float* __restrict__ kptv)
{
  const int idx = blockIdx.x*256 + threadIdx.x;  // 65536
  float a = 0.f;
  #pragma unroll
  for (int g=0; g<16; ++g) a += part[(size_t)g*65536 + idx];
  kptv[idx] = a;
}

// ---------------- attention out + proj + residuals -> xo (stored in d_out)
__global__ __launch_bounds__(256) void k_attn(
    const float* __restrict__ kqv, const float* __restrict__ qp,
    const float* __restrict__ kpsum, const float* __restrict__ kptv,
    const float* __restrict__ projw, const float* __restrict__ projb,
    const float* __restrict__ convX, float* __restrict__ xo)
{
  __shared__ float pw[64*65];
  __shared__ float ktv[64*33];
  __shared__ float ks[32];
  __shared__ float tsh[4][64];
  const int t = threadIdx.x, n = t & 63, p = t >> 6;
  const int b = blockIdx.y;
  const int s = blockIdx.x*4 + p;
  for (int idx=t; idx<4096; idx+=256) pw[(idx>>6)*65 + (idx&63)] = projw[idx];
  for (int idx=t; idx<2048; idx+=256) ktv[(idx>>5)*33 + (idx&31)] = kptv[b*2048 + idx];
  if (t < 32) ks[t] = kpsum[b*MM + t];
  __syncthreads();
  const float* qpp = qp + ((size_t)b*TT + s)*MM;
  float D = 0.f, num = 0.f;
  #pragma unroll 8
  for (int m=0;m<32;++m){
    float q = qpp[m];
    D   += q*ks[m];
    num += q*ktv[n*33+m];
  }
  tsh[p][n] = num / (D + 1e-8f);
  __syncthreads();
  float acc = projb[n];
  #pragma unroll 8
  for (int j=0;j<64;++j) acc += tsh[p][j]*pw[n*65+j];
  const size_t off = ((size_t)b*TT + s)*64 + n;
  const float vv = kqv[((size_t)b*TT + s)*KQVN + 128 + n];
  xo[off] = vv + acc + convX[off];
}

// ---------------- final MLP, in place on d_out: out = xo + mlp(ln(xo))
__global__ __launch_bounds__(256) void k_mlp(
    const float* __restrict__ ln2_g, const float* __restrict__ ln2_b,
    const float* __restrict__ w1, const float* __restrict__ b1,
    const float* __restrict__ w2, const float* __restrict__ b2,
    float* __restrict__ out)
{
  __shared__ float w1s[64*65], w2s[64*65];
  __shared__ float lnsh[4][64], h1sh[4][64];
  const int t = threadIdx.x, n = t & 63, p = t >> 6;
  const int b = blockIdx.y;
  const int s = blockIdx.x*4 + p;
  for (int idx=t; idx<4096; idx+=256){
    int r = idx >> 6, c = idx & 63;
    w1s[r*65+c] = w1[idx];
    w2s[r*65+c] = w2[idx];
  }
  const size_t off = ((size_t)b*TT + s)*64;
  const float xv = out[off + n];
  float s1 = xv, s2 = xv*xv;
  #pragma unroll
  for (int o=32;o;o>>=1){
    s1 += __shfl_xor(s1, o, 64);
    s2 += __shfl_xor(s2, o, 64);
  }
  float mu = s1*(1.f/64.f);
  float rs = rsqrtf(s2*(1.f/64.f) - mu*mu + 1e-5f);
  float ln = (xv - mu)*rs*ln2_g[n] + ln2_b[n];
  lnsh[p][n] = ln;
  __syncthreads();
  float acc = b1[n];
  #pragma unroll 8
  for (int c=0;c<64;++c) acc += lnsh[p][c]*w1s[n*65+c];
  acc = geluf(acc);
  h1sh[p][n] = acc;
  __syncthreads();
  float acc2 = b2[n];
  #pragma unroll 8
  for (int c=0;c<64;++c) acc2 += h1sh[p][c]*w2s[n*65+c];
  out[off + n] = xv + acc2;
}

extern "C" void kernel_launch(void* const* d_in, const int* in_sizes, int n_in,
                              void* d_out, int out_size, void* d_ws, size_t ws_size,
                              hipStream_t stream)
{
  const float* x      = (const float*)d_in[0];
  const float* prm_w  = (const float*)d_in[1];
  const float* prm_b  = (const float*)d_in[2];
  const float* pcm_w1 = (const float*)d_in[3];
  const float* pcm_b1 = (const float*)d_in[4];
  const float* pcm_w2 = (const float*)d_in[5];
  const float* pcm_b2 = (const float*)d_in[6];
  const float* bn_g   = (const float*)d_in[7];
  const float* bn_b   = (const float*)d_in[8];
  const float* bn_mean= (const float*)d_in[9];
  const float* bn_var = (const float*)d_in[10];
  const float* pcm_w3 = (const float*)d_in[11];
  const float* pcm_b3 = (const float*)d_in[12];
  const float* ln1_g  = (const float*)d_in[13];
  const float* ln1_b  = (const float*)d_in[14];
  const float* kqv_w  = (const float*)d_in[15];
  const float* kqv_b  = (const float*)d_in[16];
  const float* w_perf = (const float*)d_in[17];
  const float* proj_w = (const float*)d_in[18];
  const float* proj_b = (const float*)d_in[19];
  const float* ln2_g  = (const float*)d_in[20];
  const float* ln2_b  = (const float*)d_in[21];
  const float* mlp_w1 = (const float*)d_in[22];
  const float* mlp_b1 = (const float*)d_in[23];
  const float* mlp_w2 = (const float*)d_in[24];
  const float* mlp_b2 = (const float*)d_in[25];

  float* ws = (float*)d_ws;
  float* c1    = ws + OFF_C1;
  float* convX = ws + OFF_CONVX;
  float* kqv   = ws + OFF_KQV;
  float* c2    = ws + OFF_C2;
  float* kp    = ws + OFF_KP;
  float* qp    = ws + OFF_QP;
  float* part  = ws + OFF_PART;
  float* kptv  = ws + OFF_KPTV;
  float* kpsum = ws + OFF_KPSUM;
  float* out   = (float*)d_out;

  // CNN stem
  k_conv1<<<dim3(49,64,BB), 256, 0, stream>>>(x, pcm_w1, pcm_b1, c1);
  k_conv2<<<dim3(13,16,BB), 256, 0, stream>>>(c1, pcm_w2, pcm_b2, bn_g, bn_b,
                                              bn_mean, bn_var, c2);
  k_conv3<<<dim3(784,BB), 256, 0, stream>>>(c2, pcm_w3, pcm_b3, convX);
  // PRM + LN + KQV (fused)
  k_prm_ln_kqv<<<dim3(224,BB), 256, 0, stream>>>(x, prm_w, prm_b, ln1_g, ln1_b,
                                                 kqv_w, kqv_b, kqv);
  // Performer features
  k_prmexp<<<dim3(392,BB,2), 256, 0, stream>>>(kqv, w_perf, kp, qp);
  k_kpsum<<<dim3(BB), 256, 0, stream>>>(kp, kpsum);
  k_kptv<<<dim3(16,BB), 256, 0, stream>>>(kqv, kp, part);
  k_kptv_red<<<dim3(256), 256, 0, stream>>>(part, kptv);
  // attention output + residuals -> xo in d_out
  k_attn<<<dim3(784,BB), 256, 0, stream>>>(kqv, qp, kpsum, kptv, proj_w, proj_b,
                                           convX, out);
  // final MLP in place
  k_mlp<<<dim3(784,BB), 256, 0, stream>>>(ln2_g, ln2_b, mlp_w1, mlp_b1,
                                          mlp_w2, mlp_b2, out);
}

// Round 2
// 2346.605 us; speedup vs baseline: 5.9321x; 5.9321x over previous
//
#include <hip/hip_runtime.h>
#include <hip/hip_bf16.h>
#include <cstddef>

// Problem constants
#define BB    32
#define IMG   224
#define CIN   3
#define ED    64
#define TD    64
#define MM    32
#define HP    56
#define TT    3136      // 56*56
#define C4    256       // 4*ED
#define KQVN  192       // 3*TD

// workspace offsets (floats)
#define OFF_C1     0u           // 32*64*112*112 = 25,690,112   [conv1 out; dead after conv2]
#define OFF_CONVX  0u           // 32*3136*64    = 6,422,528    [after conv3]
#define OFF_KQV    6422528u     // 32*3136*192   = 19,267,584
#define OFF_C2     25690112u    // 32*64*56*56   = 6,422,528    [dead after conv3]
#define OFF_KP     25690112u    // 32*3136*32    = 3,211,264
#define OFF_QP     28901376u    // 32*3136*32    = 3,211,264
#define OFF_PART   32112640u    // 16*32*64*32   = 1,048,576  [kptv partials, live only late]
#define OFF_KPTV   33161216u    // 32*64*32      = 65,536
#define OFF_KPSUM  33226752u    // 32*32         = 1,024
// transposed weights live in the PART region (dead until k_kptv, which runs after all users)
#define OFF_WT3    (OFF_PART)             // 64*9*64   = 36,864
#define OFF_WPT    (OFF_PART + 36864u)    // 4*147*64  = 37,632
#define OFF_WKT    (OFF_PART + 74496u)    // 256*192   = 49,152

__device__ __forceinline__ float geluf(float v){
  return 0.5f*v*(1.f + erff(v*0.70710678118654752f));
}
__device__ __forceinline__ float siluf(float v){
  return v/(1.f + expf(-v));
}

// ---------------- weight transposes (lane-coalesced layouts for conv3/prm/kqv)
__global__ __launch_bounds__(256) void k_wtrans(
    const float* __restrict__ pcm_w3, const float* __restrict__ prm_w,
    const float* __restrict__ kqv_w, float* __restrict__ wt3,
    float* __restrict__ wpt, float* __restrict__ wkt)
{
  int idx = blockIdx.x*256 + threadIdx.x;
  if (idx < 36864){
    int oc = idx & 63, r = idx >> 6;      // r = ci*9+k
    int ci = r/9, k = r - ci*9;
    wt3[idx] = pcm_w3[(oc*64 + ci)*9 + k];
  } else if (idx < 74496){
    int i2 = idx - 36864;
    int oc = i2 & 63, r = i2 >> 6;        // r = i*147+tap
    int i = r/147, tap = r - i*147;
    wpt[i2] = prm_w[(i*64 + oc)*147 + tap];
  } else if (idx < 123648){
    int i3 = idx - 74496;                 // i3 = c*192 + j
    int c = i3/192, j = i3 - c*192;
    wkt[i3] = kqv_w[j*256 + c];
  }
}

// ---------------- conv1: x(32,3,224,224) -> c1(32,64,112,112), 3x3 s2 p1, SiLU
__global__ __launch_bounds__(256) void k_conv1(
    const float* __restrict__ x, const float* __restrict__ w,
    const float* __restrict__ bias, float* __restrict__ c1)
{
  const int oc = blockIdx.y, b = blockIdx.z;
  const int s = blockIdx.x*256 + threadIdx.x;   // 0..12543
  const int oh = s/112, ow = s - (s/112)*112;
  const float* wp = w + oc*27;
  const float* xb = x + (size_t)b*CIN*IMG*IMG;
  float acc = bias[oc];
  for (int ci=0; ci<3; ++ci){
    for (int kh=0; kh<3; ++kh){
      int ih = oh*2 - 1 + kh;
      if ((unsigned)ih >= (unsigned)IMG) continue;
      for (int kw=0; kw<3; ++kw){
        int iw = ow*2 - 1 + kw;
        if ((unsigned)iw >= (unsigned)IMG) continue;
        acc += wp[(ci*3+kh)*3+kw] * xb[(ci*IMG+ih)*IMG+iw];
      }
    }
  }
  c1[(((size_t)b*64+oc)*112+oh)*112+ow] = siluf(acc);
}

// ---------------- conv2: c1 -> c2(32,64,56,56), 3x3 s2 p1, BN+SiLU; 4 oc/thread
__global__ __launch_bounds__(256) void k_conv2(
    const float* __restrict__ c1, const float* __restrict__ w,
    const float* __restrict__ bias, const float* __restrict__ g,
    const float* __restrict__ bb, const float* __restrict__ mean,
    const float* __restrict__ var, float* __restrict__ c2)
{
  const int ocg = blockIdx.y, b = blockIdx.z;
  const int s = blockIdx.x*256 + threadIdx.x;
  if (s >= TT) return;
  const int oh = s/HP, ow = s - (s/HP)*HP;
  const int oc0 = ocg*4;
  float acc[4];
  #pragma unroll
  for (int u=0;u<4;++u) acc[u] = bias[oc0+u];
  const float* cb = c1 + (size_t)b*64*112*112;
  for (int ci=0; ci<64; ++ci){
    const float* xp = cb + ci*12544;
    const float* wq = w + ci*9;   // + oc*576
    for (int kh=0; kh<3; ++kh){
      int ih = oh*2 - 1 + kh;
      if ((unsigned)ih >= 112u) continue;
      for (int kw=0; kw<3; ++kw){
        int iw = ow*2 - 1 + kw;
        if ((unsigned)iw >= 112u) continue;
        float xv = xp[ih*112+iw];
        #pragma unroll
        for (int u=0;u<4;++u)
          acc[u] += wq[(oc0+u)*576 + kh*3+kw] * xv;
      }
    }
  }
  #pragma unroll
  for (int u=0;u<4;++u){
    int oc = oc0+u;
    float inv = g[oc]*rsqrtf(var[oc] + 1e-5f);
    float v = (acc[u] - mean[oc])*inv + bb[oc];
    c2[(((size_t)b*64+oc)*HP+oh)*HP+ow] = siluf(v);
  }
}

// ---------------- conv3: c2 -> convX(32,3136,64) NHWC, 3x3 s1 p1, SiLU
// tiled: block = (b, 8x8 spatial tile), all 64 ci staged in LDS, coalesced weights
__global__ __launch_bounds__(256) void k_conv3(
    const float* __restrict__ c2, const float* __restrict__ wt3,
    const float* __restrict__ bias, float* __restrict__ convX)
{
  __shared__ __align__(16) float xs[64][10][12];
  const int b = blockIdx.y;
  const int th = blockIdx.x / 7, tw = blockIdx.x - th*7;
  const int oh0 = th*8, ow0 = tw*8;
  const int t = threadIdx.x;
  const float* cb = c2 + (size_t)b*64*TT;
  for (int idx = t; idx < 6400; idx += 256){
    int ci = idx/100, rem = idx - ci*100;
    int r = rem/10, c = rem - r*10;
    int ih = oh0 - 1 + r, iw = ow0 - 1 + c;
    float v = 0.f;
    if ((unsigned)ih < 56u && (unsigned)iw < 56u)
      v = cb[(ci*56 + ih)*56 + iw];
    xs[ci][r][c] = v;
  }
  __syncthreads();
  const int oc = t & 63, g = t >> 6;   // g: row-pair 2g, 2g+1
  float acc[16];
  const float bv = bias[oc];
  #pragma unroll
  for (int u=0;u<16;++u) acc[u] = bv;
  for (int ci=0; ci<64; ++ci){
    float xr[4][10];
    #pragma unroll
    for (int r=0;r<4;++r){
      const float4* rp = (const float4*)&xs[ci][2*g+r][0];
      float4 a = rp[0], bq = rp[1];
      float2 e = *(const float2*)&xs[ci][2*g+r][8];
      xr[r][0]=a.x; xr[r][1]=a.y; xr[r][2]=a.z; xr[r][3]=a.w;
      xr[r][4]=bq.x; xr[r][5]=bq.y; xr[r][6]=bq.z; xr[r][7]=bq.w;
      xr[r][8]=e.x; xr[r][9]=e.y;
    }
    const float* wq = wt3 + ci*576 + oc;
    #pragma unroll
    for (int k=0;k<9;++k){
      const int kh = k/3, kw = k - kh*3;
      const float wv = wq[k*64];
      #pragma unroll
      for (int pr=0;pr<2;++pr)
        #pragma unroll
        for (int pc=0;pc<8;++pc)
          acc[pr*8+pc] += wv * xr[pr+kh][pc+kw];
    }
  }
  #pragma unroll
  for (int pr=0;pr<2;++pr)
    #pragma unroll
    for (int pc=0;pc<8;++pc){
      int s = (oh0 + 2*g + pr)*HP + ow0 + pc;
      convX[((size_t)b*TT + s)*64 + oc] = siluf(acc[pr*8+pc]);
    }
}

// ---------------- fused PRM convs + GELU + LN + KQV. one block = (oh, 14-wide ow strip)
__global__ __launch_bounds__(256) void k_prm_ln_kqv(
    const float* __restrict__ x, const float* __restrict__ wpt,
    const float* __restrict__ prm_b, const float* __restrict__ ln_g,
    const float* __restrict__ ln_b, const float* __restrict__ wkt,
    const float* __restrict__ kqv_b, float* __restrict__ kqv)
{
  __shared__ __align__(16) float xt[3][25][80];
  __shared__ __align__(16) float xnsh[14][256];
  __shared__ float mu_s[14], rs_s[14];
  const int t = threadIdx.x;
  const int b = blockIdx.y;
  const int oh  = blockIdx.x >> 2;
  const int owt = blockIdx.x & 3;
  const int ow0 = owt*14;
  const int ih0 = oh*4 - 11;
  const int iw0 = ow0*4 - 11;

  // stage zero-padded x tile [3][25][80]
  const float* xb = x + (size_t)b*CIN*IMG*IMG;
  for (int idx = t; idx < 6000; idx += 256){
    int ci  = idx / 2000;
    int rem = idx - ci*2000;
    int r   = rem / 80;
    int cc  = rem - r*80;
    int ih = ih0 + r, iw = iw0 + cc;
    float val = 0.f;
    if ((unsigned)ih < (unsigned)IMG && (unsigned)iw < (unsigned)IMG)
      val = xb[(ci*IMG+ih)*IMG+iw];
    xt[ci][r][cc] = val;
  }
  __syncthreads();

  const int i = t >> 6, oc = t & 63;
  const int d = i + 1;
  const int r0 = 12 - 3*d;   // tile-relative base offset (pad = 3d-1)
  float v[14];
  const float bi = prm_b[i*64+oc];
  #pragma unroll
  for (int p=0;p<14;++p) v[p] = bi;
  const float* wq = wpt + (i*147)*64 + oc;   // transposed: [tap][oc], coalesced

  for (int ci=0; ci<3; ++ci){
    for (int kh=0; kh<7; ++kh){
      const int rh = r0 + kh*d;
      const float* xrow = &xt[ci][rh][0];
      #pragma unroll
      for (int kw=0; kw<7; ++kw){
        const float wv = wq[((ci*7+kh)*7+kw)*64];
        const int rw = r0 + kw*d;
        #pragma unroll
        for (int p=0;p<14;++p)
          v[p] += wv * xrow[p*4 + rw];
      }
    }
  }
  // GELU + stash for LN
  #pragma unroll
  for (int p=0;p<14;++p){
    float a = geluf(v[p]);
    v[p] = a;
    xnsh[p][t] = a;
  }
  __syncthreads();

  // LN stats: wave w handles p = w, w+4, ...
  const int wvid = t >> 6, lane = t & 63;
  for (int p = wvid; p < 14; p += 4){
    float s1 = 0.f, s2 = 0.f;
    for (int c = lane; c < 256; c += 64){
      float u = xnsh[p][c];
      s1 += u; s2 += u*u;
    }
    #pragma unroll
    for (int o=32;o;o>>=1){
      s1 += __shfl_down(s1, o, 64);
      s2 += __shfl_down(s2, o, 64);
    }
    if (lane == 0){
      float mu = s1*(1.f/256.f);
      float va = s2*(1.f/256.f) - mu*mu;
      mu_s[p] = mu;
      rs_s[p] = rsqrtf(va + 1e-5f);
    }
  }
  __syncthreads();
  const float lg = ln_g[t], lb = ln_b[t];
  #pragma unroll
  for (int p=0;p<14;++p)
    xnsh[p][t] = (v[p] - mu_s[p])*rs_s[p]*lg + lb;
  __syncthreads();

  // KQV: 672 tasks = 14 p x 48 j-quads; weights transposed [c][j] -> coalesced f4
  const int s_base = oh*HP + ow0;
  const float4* wrow = (const float4*)wkt;   // [c*48 + jq]
  for (int task = t; task < 672; task += 256){
    int p = task/48, jq = task - p*48;
    float4 acc4 = *(const float4*)(kqv_b + jq*4);
    const float4* xr4 = (const float4*)&xnsh[p][0];
    for (int c4=0;c4<64;++c4){
      float4 xv = xr4[c4];
      float4 w0 = wrow[(c4*4+0)*48 + jq];
      float4 w1 = wrow[(c4*4+1)*48 + jq];
      float4 w2 = wrow[(c4*4+2)*48 + jq];
      float4 w3 = wrow[(c4*4+3)*48 + jq];
      acc4.x += xv.x*w0.x + xv.y*w1.x + xv.z*w2.x + xv.w*w3.x;
      acc4.y += xv.x*w0.y + xv.y*w1.y + xv.z*w2.y + xv.w*w3.y;
      acc4.z += xv.x*w0.z + xv.y*w1.z + xv.z*w2.z + xv.w*w3.z;
      acc4.w += xv.x*w0.w + xv.y*w1.w + xv.z*w2.w + xv.w*w3.w;
    }
    *(float4*)(kqv + ((size_t)b*TT + s_base + p)*KQVN + jq*4) = acc4;
  }
}

// ---------------- prm_exp: kqv -> kp (z.z=0) / qp (z.z=1)
__global__ __launch_bounds__(256) void k_prmexp(
    const float* __restrict__ kqv, const float* __restrict__ wperf,
    float* __restrict__ kp, float* __restrict__ qp)
{
  const int b = blockIdx.y;
  const int which = blockIdx.z;
  const int m = threadIdx.x & 31, pl = threadIdx.x >> 5;
  const int s = blockIdx.x*8 + pl;
  const float* z = kqv + ((size_t)b*TT + s)*KQVN + which*64;
  const float* wm = wperf + m*64;
  float xd = 0.f, wtx = 0.f;
  for (int i2=0;i2<64;i2+=4){
    float4 z4 = *(const float4*)(z+i2);
    float4 w4 = *(const float4*)(wm+i2);
    xd  += z4.x*z4.x + z4.y*z4.y + z4.z*z4.z + z4.w*z4.w;
    wtx += z4.x*w4.x + z4.y*w4.y + z4.z*w4.z + z4.w*w4.w;
  }
  float outv = expf(wtx - 0.5f*xd) * 0.17677669529663687f; // 1/sqrt(32)
  float* dst = which ? qp : kp;
  dst[((size_t)b*TT + s)*MM + m] = outv;
}

// ---------------- kpsum[b][m] = sum_t kp[b][t][m]
__global__ __launch_bounds__(256) void k_kpsum(
    const float* __restrict__ kp, float* __restrict__ kpsum)
{
  const int b = blockIdx.x;
  const int m = threadIdx.x & 31, g = threadIdx.x >> 5;
  __shared__ float part[8][32];
  float s = 0.f;
  for (int tt = g; tt < TT; tt += 8)
    s += kp[((size_t)b*TT + tt)*MM + m];
  part[g][m] = s;
  __syncthreads();
  if (threadIdx.x < 32){
    float a = 0.f;
    #pragma unroll
    for (int g2=0;g2<8;++g2) a += part[g2][threadIdx.x];
    kpsum[b*MM + threadIdx.x] = a;
  }
}

// ---------------- kptv partials: part[g][b][n][m] over t-range
__global__ __launch_bounds__(256) void k_kptv(
    const float* __restrict__ kqv, const float* __restrict__ kp,
    float* __restrict__ part)
{
  const int b = blockIdx.y, g = blockIdx.x;   // 16 groups of 196
  const int n = threadIdx.x & 63, mg = threadIdx.x >> 6; // mg: m-octet
  float acc[8] = {0,0,0,0,0,0,0,0};
  for (int tt = g*196; tt < (g+1)*196; ++tt){
    float vv = kqv[((size_t)b*TT + tt)*KQVN + 128 + n];
    const float4* kp4 = (const float4*)(kp + ((size_t)b*TT + tt)*MM + mg*8);
    float4 a0 = kp4[0], a1 = kp4[1];
    acc[0] += vv*a0.x; acc[1] += vv*a0.y; acc[2] += vv*a0.z; acc[3] += vv*a0.w;
    acc[4] += vv*a1.x; acc[5] += vv*a1.y; acc[6] += vv*a1.z; acc[7] += vv*a1.w;
  }
  #pragma unroll
  for (int j=0;j<8;++j)
    part[(((size_t)g*BB + b)*64 + n)*MM + mg*8 + j] = acc[j];
}

__global__ __launch_bounds__(256) void k_kptv_red(
    const float* __restrict__ part, float* __restrict__ kptv)
{
  const int idx = blockIdx.x*256 + threadIdx.x;  // 65536
  float a = 0.f;
  #pragma unroll
  for (int g=0; g<16; ++g) a += part[(size_t)g*65536 + idx];
  kptv[idx] = a;
}

// ---------------- attention out + proj + residuals -> xo (stored in d_out)
__global__ __launch_bounds__(256) void k_attn(
    const float* __restrict__ kqv, const float* __restrict__ qp,
    const float* __restrict__ kpsum, const float* __restrict__ kptv,
    const float* __restrict__ projw, const float* __restrict__ projb,
    const float* __restrict__ convX, float* __restrict__ xo)
{
  __shared__ float pw[64*65];
  __shared__ float ktv[64*33];
  __shared__ float ks[32];
  __shared__ float tsh[4][64];
  const int t = threadIdx.x, n = t & 63, p = t >> 6;
  const int b = blockIdx.y;
  const int s = blockIdx.x*4 + p;
  for (int idx=t; idx<4096; idx+=256) pw[(idx>>6)*65 + (idx&63)] = projw[idx];
  for (int idx=t; idx<2048; idx+=256) ktv[(idx>>5)*33 + (idx&31)] = kptv[b*2048 + idx];
  if (t < 32) ks[t] = kpsum[b*MM + t];
  __syncthreads();
  const float* qpp = qp + ((size_t)b*TT + s)*MM;
  float D = 0.f, num = 0.f;
  #pragma unroll 8
  for (int m=0;m<32;++m){
    float q = qpp[m];
    D   += q*ks[m];
    num += q*ktv[n*33+m];
  }
  tsh[p][n] = num / (D + 1e-8f);
  __syncthreads();
  float acc = projb[n];
  #pragma unroll 8
  for (int j=0;j<64;++j) acc += tsh[p][j]*pw[n*65+j];
  const size_t off = ((size_t)b*TT + s)*64 + n;
  const float vv = kqv[((size_t)b*TT + s)*KQVN + 128 + n];
  xo[off] = vv + acc + convX[off];
}

// ---------------- final MLP, in place on d_out: out = xo + mlp(ln(xo))
__global__ __launch_bounds__(256) void k_mlp(
    const float* __restrict__ ln2_g, const float* __restrict__ ln2_b,
    const float* __restrict__ w1, const float* __restrict__ b1,
    const float* __restrict__ w2, const float* __restrict__ b2,
    float* __restrict__ out)
{
  __shared__ float w1s[64*65], w2s[64*65];
  __shared__ float lnsh[4][64], h1sh[4][64];
  const int t = threadIdx.x, n = t & 63, p = t >> 6;
  const int b = blockIdx.y;
  const int s = blockIdx.x*4 + p;
  for (int idx=t; idx<4096; idx+=256){
    int r = idx >> 6, c = idx & 63;
    w1s[r*65+c] = w1[idx];
    w2s[r*65+c] = w2[idx];
  }
  const size_t off = ((size_t)b*TT + s)*64;
  const float xv = out[off + n];
  float s1 = xv, s2 = xv*xv;
  #pragma unroll
  for (int o=32;o;o>>=1){
    s1 += __shfl_xor(s1, o, 64);
    s2 += __shfl_xor(s2, o, 64);
  }
  float mu = s1*(1.f/64.f);
  float rs = rsqrtf(s2*(1.f/64.f) - mu*mu + 1e-5f);
  float ln = (xv - mu)*rs*ln2_g[n] + ln2_b[n];
  lnsh[p][n] = ln;
  __syncthreads();
  float acc = b1[n];
  #pragma unroll 8
  for (int c=0;c<64;++c) acc += lnsh[p][c]*w1s[n*65+c];
  acc = geluf(acc);
  h1sh[p][n] = acc;
  __syncthreads();
  float acc2 = b2[n];
  #pragma unroll 8
  for (int c=0;c<64;++c) acc2 += h1sh[p][c]*w2s[n*65+c];
  out[off + n] = xv + acc2;
}

extern "C" void kernel_launch(void* const* d_in, const int* in_sizes, int n_in,
                              void* d_out, int out_size, void* d_ws, size_t ws_size,
                              hipStream_t stream)
{
  const float* x      = (const float*)d_in[0];
  const float* prm_w  = (const float*)d_in[1];
  const float* prm_b  = (const float*)d_in[2];
  const float* pcm_w1 = (const float*)d_in[3];
  const float* pcm_b1 = (const float*)d_in[4];
  const float* pcm_w2 = (const float*)d_in[5];
  const float* pcm_b2 = (const float*)d_in[6];
  const float* bn_g   = (const float*)d_in[7];
  const float* bn_b   = (const float*)d_in[8];
  const float* bn_mean= (const float*)d_in[9];
  const float* bn_var = (const float*)d_in[10];
  const float* pcm_w3 = (const float*)d_in[11];
  const float* pcm_b3 = (const float*)d_in[12];
  const float* ln1_g  = (const float*)d_in[13];
  const float* ln1_b  = (const float*)d_in[14];
  const float* kqv_w  = (const float*)d_in[15];
  const float* kqv_b  = (const float*)d_in[16];
  const float* w_perf = (const float*)d_in[17];
  const float* proj_w = (const float*)d_in[18];
  const float* proj_b = (const float*)d_in[19];
  const float* ln2_g  = (const float*)d_in[20];
  const float* ln2_b  = (const float*)d_in[21];
  const float* mlp_w1 = (const float*)d_in[22];
  const float* mlp_b1 = (const float*)d_in[23];
  const float* mlp_w2 = (const float*)d_in[24];
  const float* mlp_b2 = (const float*)d_in[25];

  float* ws = (float*)d_ws;
  float* c1    = ws + OFF_C1;
  float* convX = ws + OFF_CONVX;
  float* kqv   = ws + OFF_KQV;
  float* c2    = ws + OFF_C2;
  float* kp    = ws + OFF_KP;
  float* qp    = ws + OFF_QP;
  float* part  = ws + OFF_PART;
  float* kptv  = ws + OFF_KPTV;
  float* kpsum = ws + OFF_KPSUM;
  float* wt3   = ws + OFF_WT3;
  float* wpt   = ws + OFF_WPT;
  float* wkt   = ws + OFF_WKT;
  float* out   = (float*)d_out;

  // weight transposes (coalesced layouts); dead once k_kptv overwrites PART
  k_wtrans<<<dim3(483), 256, 0, stream>>>(pcm_w3, prm_w, kqv_w, wt3, wpt, wkt);
  // CNN stem
  k_conv1<<<dim3(49,64,BB), 256, 0, stream>>>(x, pcm_w1, pcm_b1, c1);
  k_conv2<<<dim3(13,16,BB), 256, 0, stream>>>(c1, pcm_w2, pcm_b2, bn_g, bn_b,
                                              bn_mean, bn_var, c2);
  k_conv3<<<dim3(49,BB), 256, 0, stream>>>(c2, wt3, pcm_b3, convX);
  // PRM + LN + KQV (fused)
  k_prm_ln_kqv<<<dim3(224,BB), 256, 0, stream>>>(x, wpt, prm_b, ln1_g, ln1_b,
                                                 wkt, kqv_b, kqv);
  // Performer features
  k_prmexp<<<dim3(392,BB,2), 256, 0, stream>>>(kqv, w_perf, kp, qp);
  k_kpsum<<<dim3(BB), 256, 0, stream>>>(kp, kpsum);
  k_kptv<<<dim3(16,BB), 256, 0, stream>>>(kqv, kp, part);
  k_kptv_red<<<dim3(256), 256, 0, stream>>>(part, kptv);
  // attention output + residuals -> xo in d_out
  k_attn<<<dim3(784,BB), 256, 0, stream>>>(kqv, qp, kpsum, kptv, proj_w, proj_b,
                                           convX, out);
  // final MLP in place
  k_mlp<<<dim3(784,BB), 256, 0, stream>>>(ln2_g, ln2_b, mlp_w1, mlp_b1,
                                          mlp_w2, mlp_b2, out);
}

// Round 3
// 1092.224 us; speedup vs baseline: 12.7449x; 2.1485x over previous
//
#include <hip/hip_runtime.h>
#include <hip/hip_bf16.h>
#include <cstddef>

// Problem constants
#define BB    32
#define IMG   224
#define CIN   3
#define ED    64
#define TD    64
#define MM    32
#define HP    56
#define TT    3136      // 56*56
#define C4    256       // 4*ED
#define KQVN  192       // 3*TD

typedef __attribute__((ext_vector_type(8))) short bf16x8;
typedef __attribute__((ext_vector_type(4))) float f32x4;

// workspace offsets (float units). Timeline:
//  conv1->c1[0,25.69M) ; conv2->c2[25.69M,32.11M) ; conv3->convX[0,6.42M)
//  prm_ln->xn(bf16)[6.42M,19.27M) ; gemm->v[19.27M,25.69M) kp[25.69M,28.9M) qp[28.9M,32.11M)
//  kptv->part[32.11M,33.16M) (weights dead by then)
#define OFF_C1     0u
#define OFF_C2     25690112u
#define OFF_CONVX  0u
#define OFF_XN     6422528u     // bf16 buffer: 25,690,112 elems (12,845,056 f-equiv)
#define OFF_V      19267584u    // 6,422,528
#define OFF_KP     25690112u    // 3,211,264
#define OFF_QP     28901376u    // 3,211,264
#define OFF_PART   32112640u    // 1,048,576
#define OFF_KPTV   33161216u    // 65,536
#define OFF_KPSUM  33226752u    // 1,024
// transposed weights live in PART region (dead until k_kptv)
#define OFF_WT3    (OFF_PART)              // 36,864 f
#define OFF_WPT    (OFF_PART + 36864u)     // 37,632 f
#define OFF_WC2    (OFF_PART + 74496u)     // 36,864 f
#define OFF_WKB    (OFF_PART + 111360u)    // 49,152 bf16 = 24,576 f

__device__ __forceinline__ float geluf(float v){
  return 0.5f*v*(1.f + erff(v*0.70710678118654752f));
}
__device__ __forceinline__ float siluf(float v){
  return v/(1.f + expf(-v));
}

// ---------------- weight transposes / casts
__global__ __launch_bounds__(256) void k_wtrans(
    const float* __restrict__ pcm_w3, const float* __restrict__ prm_w,
    const float* __restrict__ pcm_w2, const float* __restrict__ kqv_w,
    float* __restrict__ wt3, float* __restrict__ wpt, float* __restrict__ wc2,
    __hip_bfloat16* __restrict__ wkb)
{
  int idx = blockIdx.x*256 + threadIdx.x;
  if (idx < 36864){
    int oc = idx & 63, r = idx >> 6;      // r = ci*9+k
    int ci = r/9, k = r - ci*9;
    wt3[idx] = pcm_w3[(oc*64 + ci)*9 + k];
  } else if (idx < 74496){
    int i2 = idx - 36864;
    int oc = i2 & 63, r = i2 >> 6;        // r = i*147+tap
    int i = r/147, tap = r - i*147;
    wpt[i2] = prm_w[(i*64 + oc)*147 + tap];
  } else if (idx < 111360){
    int i3 = idx - 74496;
    int oc = i3 & 63, r = i3 >> 6;        // r = ci*9+k
    int ci = r/9, k = r - ci*9;
    wc2[i3] = pcm_w2[(oc*64 + ci)*9 + k];
  } else if (idx < 160512){
    int i4 = idx - 111360;                // [j][c] row-major, straight cast
    wkb[i4] = __float2bfloat16(kqv_w[i4]);
  }
}

// ---------------- conv1: x(32,3,224,224) -> c1(32,64,112,112), 3x3 s2 p1, SiLU
// block = 2 output rows; x tile + all weights in LDS; x read once total
__global__ __launch_bounds__(256) void k_conv1(
    const float* __restrict__ x, const float* __restrict__ w,
    const float* __restrict__ bias, float* __restrict__ c1)
{
  __shared__ __align__(16) float xs[3][5][226];
  __shared__ float ws1[1728];
  __shared__ float bs[64];
  const int t = threadIdx.x;
  const int b = blockIdx.y;
  const int oh0 = blockIdx.x*2;
  const int ih0 = oh0*2 - 1;
  const float* xb = x + (size_t)b*CIN*IMG*IMG;
  for (int idx = t; idx < 3390; idx += 256){
    int ci = idx/1130, rem = idx - ci*1130;
    int r = rem/226, c = rem - r*226;
    int ih = ih0 + r, iw = c - 1;
    float v = 0.f;
    if ((unsigned)ih < (unsigned)IMG && (unsigned)iw < (unsigned)IMG)
      v = xb[(ci*IMG+ih)*IMG+iw];
    xs[ci][r][c] = v;
  }
  for (int idx = t; idx < 1728; idx += 256) ws1[idx] = w[idx];
  if (t < 64) bs[t] = bias[t];
  __syncthreads();
  if (t < 224){
    const int orow = t/112, ow = t - orow*112;
    const int rb = orow*2, cb = ow*2;
    float xr[3][3][3];
    #pragma unroll
    for (int ci=0;ci<3;++ci)
      #pragma unroll
      for (int kh=0;kh<3;++kh)
        #pragma unroll
        for (int kw=0;kw<3;++kw)
          xr[ci][kh][kw] = xs[ci][rb+kh][cb+kw];
    const int oh = oh0 + orow;
    for (int oc=0; oc<64; ++oc){
      float acc = bs[oc];
      const float* wp = &ws1[oc*27];
      #pragma unroll
      for (int ci=0;ci<3;++ci)
        #pragma unroll
        for (int kh=0;kh<3;++kh)
          #pragma unroll
          for (int kw=0;kw<3;++kw)
            acc += wp[(ci*3+kh)*3+kw]*xr[ci][kh][kw];
      c1[(((size_t)b*64+oc)*112+oh)*112+ow] = siluf(acc);
    }
  }
}

// ---------------- conv2: c1 -> c2(32,64,56,56), 3x3 s2 p1, BN+SiLU
// tiled 8x8, ci chunks of 16 staged in LDS, transposed weights
__global__ __launch_bounds__(256) void k_conv2(
    const float* __restrict__ c1, const float* __restrict__ wc2,
    const float* __restrict__ bias, const float* __restrict__ g,
    const float* __restrict__ bb, const float* __restrict__ mean,
    const float* __restrict__ var, float* __restrict__ c2)
{
  __shared__ __align__(16) float xs2[16][17][20];
  const int b = blockIdx.y;
  const int th = blockIdx.x / 7, tw = blockIdx.x - th*7;
  const int oh0 = th*8, ow0 = tw*8;
  const int t = threadIdx.x;
  const int oc = t & 63, gg = t >> 6;
  float acc[16];
  const float bv = bias[oc];
  #pragma unroll
  for (int u=0;u<16;++u) acc[u] = bv;
  const int ih0 = oh0*2 - 1, iw0 = ow0*2 - 1;
  for (int cg=0; cg<4; ++cg){
    for (int idx = t; idx < 4624; idx += 256){
      int ci = idx/289, rem = idx - ci*289;
      int r = rem/17, c = rem - r*17;
      int ih = ih0 + r, iw = iw0 + c;
      float v = 0.f;
      if ((unsigned)ih < 112u && (unsigned)iw < 112u)
        v = c1[(((size_t)b*64 + cg*16+ci)*112 + ih)*112 + iw];
      xs2[ci][r][c] = v;
    }
    __syncthreads();
    for (int ci=0; ci<16; ++ci){
      float xr[5][17];
      #pragma unroll
      for (int rr=0;rr<5;++rr){
        const float4* rp = (const float4*)&xs2[ci][4*gg+rr][0];
        float4 a0 = rp[0], a1 = rp[1], a2 = rp[2], a3 = rp[3];
        xr[rr][0]=a0.x; xr[rr][1]=a0.y; xr[rr][2]=a0.z; xr[rr][3]=a0.w;
        xr[rr][4]=a1.x; xr[rr][5]=a1.y; xr[rr][6]=a1.z; xr[rr][7]=a1.w;
        xr[rr][8]=a2.x; xr[rr][9]=a2.y; xr[rr][10]=a2.z; xr[rr][11]=a2.w;
        xr[rr][12]=a3.x; xr[rr][13]=a3.y; xr[rr][14]=a3.z; xr[rr][15]=a3.w;
        xr[rr][16]=xs2[ci][4*gg+rr][16];
      }
      const float* wq = wc2 + ((cg*16+ci)*9)*64 + oc;
      #pragma unroll
      for (int k=0;k<9;++k){
        const int kh = k/3, kw = k - kh*3;
        const float wv = wq[k*64];
        #pragma unroll
        for (int pr=0;pr<2;++pr)
          #pragma unroll
          for (int pc=0;pc<8;++pc)
            acc[pr*8+pc] += wv * xr[2*pr+kh][2*pc+kw];
      }
    }
    __syncthreads();
  }
  const float inv = g[oc]*rsqrtf(var[oc] + 1e-5f);
  const float mn = mean[oc], bo = bb[oc];
  #pragma unroll
  for (int pr=0;pr<2;++pr)
    #pragma unroll
    for (int pc=0;pc<8;++pc){
      int oh = oh0 + 2*gg + pr, ow = ow0 + pc;
      float v = (acc[pr*8+pc] - mn)*inv + bo;
      c2[(((size_t)b*64+oc)*HP+oh)*HP+ow] = siluf(v);
    }
}

// ---------------- conv3: c2 -> convX(32,3136,64) NHWC, 3x3 s1 p1, SiLU
__global__ __launch_bounds__(256) void k_conv3(
    const float* __restrict__ c2, const float* __restrict__ wt3,
    const float* __restrict__ bias, float* __restrict__ convX)
{
  __shared__ __align__(16) float xs[64][10][12];
  const int b = blockIdx.y;
  const int th = blockIdx.x / 7, tw = blockIdx.x - th*7;
  const int oh0 = th*8, ow0 = tw*8;
  const int t = threadIdx.x;
  const float* cb = c2 + (size_t)b*64*TT;
  for (int idx = t; idx < 6400; idx += 256){
    int ci = idx/100, rem = idx - ci*100;
    int r = rem/10, c = rem - r*10;
    int ih = oh0 - 1 + r, iw = ow0 - 1 + c;
    float v = 0.f;
    if ((unsigned)ih < 56u && (unsigned)iw < 56u)
      v = cb[(ci*56 + ih)*56 + iw];
    xs[ci][r][c] = v;
  }
  __syncthreads();
  const int oc = t & 63, g = t >> 6;
  float acc[16];
  const float bv = bias[oc];
  #pragma unroll
  for (int u=0;u<16;++u) acc[u] = bv;
  for (int ci=0; ci<64; ++ci){
    float xr[4][10];
    #pragma unroll
    for (int r=0;r<4;++r){
      const float4* rp = (const float4*)&xs[ci][2*g+r][0];
      float4 a = rp[0], bq = rp[1];
      float2 e = *(const float2*)&xs[ci][2*g+r][8];
      xr[r][0]=a.x; xr[r][1]=a.y; xr[r][2]=a.z; xr[r][3]=a.w;
      xr[r][4]=bq.x; xr[r][5]=bq.y; xr[r][6]=bq.z; xr[r][7]=bq.w;
      xr[r][8]=e.x; xr[r][9]=e.y;
    }
    const float* wq = wt3 + ci*576 + oc;
    #pragma unroll
    for (int k=0;k<9;++k){
      const int kh = k/3, kw = k - kh*3;
      const float wv = wq[k*64];
      #pragma unroll
      for (int pr=0;pr<2;++pr)
        #pragma unroll
        for (int pc=0;pc<8;++pc)
          acc[pr*8+pc] += wv * xr[pr+kh][pc+kw];
    }
  }
  #pragma unroll
  for (int pr=0;pr<2;++pr)
    #pragma unroll
    for (int pc=0;pc<8;++pc){
      int s = (oh0 + 2*g + pr)*HP + ow0 + pc;
      convX[((size_t)b*TT + s)*64 + oc] = siluf(acc[pr*8+pc]);
    }
}

// ---------------- PRM convs + GELU + LN -> xn (bf16). one block = 14-wide strip
__global__ __launch_bounds__(256) void k_prm_ln(
    const float* __restrict__ x, const float* __restrict__ wpt,
    const float* __restrict__ prm_b, const float* __restrict__ ln_g,
    const float* __restrict__ ln_b, __hip_bfloat16* __restrict__ xn)
{
  __shared__ __align__(16) float xt[3][25][80];
  __shared__ float wred[4][14][2];
  const int t = threadIdx.x;
  const int b = blockIdx.y;
  const int oh  = blockIdx.x >> 2;
  const int owt = blockIdx.x & 3;
  const int ow0 = owt*14;
  const int ih0 = oh*4 - 11;
  const int iw0 = ow0*4 - 11;

  const float* xb = x + (size_t)b*CIN*IMG*IMG;
  for (int idx = t; idx < 6000; idx += 256){
    int ci  = idx / 2000;
    int rem = idx - ci*2000;
    int r   = rem / 80;
    int cc  = rem - r*80;
    int ih = ih0 + r, iw = iw0 + cc;
    float val = 0.f;
    if ((unsigned)ih < (unsigned)IMG && (unsigned)iw < (unsigned)IMG)
      val = xb[(ci*IMG+ih)*IMG+iw];
    xt[ci][r][cc] = val;
  }
  __syncthreads();

  const int i = t >> 6, lane = t & 63;
  const int d = i + 1;
  const int r0 = 12 - 3*d;
  float v[14];
  const float bi = prm_b[i*64+lane];
  #pragma unroll
  for (int p=0;p<14;++p) v[p] = bi;
  const float* wq = wpt + (i*147)*64 + lane;   // [tap][oc] coalesced/broadcast

  for (int ci=0; ci<3; ++ci){
    for (int kh=0; kh<7; ++kh){
      const int rh = r0 + kh*d;
      const float* xrow = &xt[ci][rh][0];
      #pragma unroll
      for (int kw=0; kw<7; ++kw){
        const float wv = wq[((ci*7+kh)*7+kw)*64];
        const int rw = r0 + kw*d;
        #pragma unroll
        for (int p=0;p<14;++p)
          v[p] += wv * xrow[p*4 + rw];
      }
    }
  }
  // GELU + per-wave LN partials via shuffles
  #pragma unroll
  for (int p=0;p<14;++p) v[p] = geluf(v[p]);
  #pragma unroll
  for (int p=0;p<14;++p){
    float s1 = v[p], s2 = v[p]*v[p];
    #pragma unroll
    for (int o=32;o;o>>=1){
      s1 += __shfl_xor(s1, o, 64);
      s2 += __shfl_xor(s2, o, 64);
    }
    if (lane == 0){ wred[i][p][0] = s1; wred[i][p][1] = s2; }
  }
  __syncthreads();
  const float lg = ln_g[t], lb = ln_b[t];
  const int s_base = oh*HP + ow0;
  #pragma unroll
  for (int p=0;p<14;++p){
    float S1 = wred[0][p][0]+wred[1][p][0]+wred[2][p][0]+wred[3][p][0];
    float S2 = wred[0][p][1]+wred[1][p][1]+wred[2][p][1]+wred[3][p][1];
    float mu = S1*(1.f/256.f);
    float rs = rsqrtf(S2*(1.f/256.f) - mu*mu + 1e-5f);
    float outv = (v[p]-mu)*rs*lg + lb;
    xn[((size_t)(b*TT + s_base + p))*256 + t] = __float2bfloat16(outv);
  }
}

// ---------------- KQV GEMM (bf16 MFMA) + fused Performer feature map
// per block: 64 positions; A = xn[64][256] bf16, B = wkb[192][256] bf16 ([N][K])
// outputs: v (f32), kp, qp
__global__ __launch_bounds__(256) void k_kqv_perf(
    const __hip_bfloat16* __restrict__ xn, const __hip_bfloat16* __restrict__ wkb,
    const float* __restrict__ kqv_b, const float* __restrict__ wperf,
    float* __restrict__ v_g, float* __restrict__ kp, float* __restrict__ qp)
{
  __shared__ __align__(16) char smem[36864];     // As[64][72] bf16 | Bs[192][72] bf16 ; reused as zq[64][129] f32
  __shared__ float wperf_s[32*65];
  __shared__ float kqvb_s[192];
  __shared__ float xd_s[128];
  ushort* As = (ushort*)smem;
  ushort* Bs = (ushort*)(smem + 9216);
  float*  zq = (float*)smem;

  const int t = threadIdx.x;
  const int m0 = blockIdx.x*64;
  const int w = t >> 6, lane = t & 63;
  const int l15 = lane & 15, hi = lane >> 4;

  for (int idx = t; idx < 2048; idx += 256)
    wperf_s[(idx>>6)*65 + (idx&63)] = wperf[idx];
  if (t < 192) kqvb_s[t] = kqv_b[t];

  f32x4 acc[12];
  #pragma unroll
  for (int nb=0;nb<12;++nb) acc[nb] = (f32x4){0.f,0.f,0.f,0.f};

  const ushort* xnu = (const ushort*)xn;
  const ushort* wku = (const ushort*)wkb;

  for (int kc=0; kc<4; ++kc){
    // stage A: 64 rows x 64 k (bf16), 512 segs of 8
    #pragma unroll
    for (int ss=0; ss<2; ++ss){
      int seg = ss*256 + t;
      int row = seg >> 3, c8 = seg & 7;
      *(uint4*)&As[row*72 + c8*8] =
        *(const uint4*)&xnu[((size_t)(m0+row))*256 + kc*64 + c8*8];
    }
    // stage B: 192 rows x 64 k, 1536 segs
    #pragma unroll
    for (int ss=0; ss<6; ++ss){
      int seg = ss*256 + t;
      int row = seg >> 3, c8 = seg & 7;
      *(uint4*)&Bs[row*72 + c8*8] =
        *(const uint4*)&wku[row*256 + kc*64 + c8*8];
    }
    __syncthreads();
    #pragma unroll
    for (int ks=0; ks<2; ++ks){
      bf16x8 a = *(const bf16x8*)&As[(16*w + l15)*72 + ks*32 + hi*8];
      #pragma unroll
      for (int nb=0;nb<12;++nb){
        bf16x8 bv = *(const bf16x8*)&Bs[(nb*16 + l15)*72 + ks*32 + hi*8];
        acc[nb] = __builtin_amdgcn_mfma_f32_16x16x32_bf16(a, bv, acc[nb], 0, 0, 0);
      }
    }
    __syncthreads();
  }

  // scatter: k,q (cols 0..127) -> zq LDS ; v (cols 128..191) -> global (+bias)
  #pragma unroll
  for (int nb=0;nb<12;++nb){
    int col = nb*16 + l15;
    float bias = kqvb_s[col];
    #pragma unroll
    for (int r=0;r<4;++r){
      int row = w*16 + hi*4 + r;
      float val = acc[nb][r] + bias;
      if (col < 128) zq[row*129 + col] = val;
      else v_g[((size_t)(m0+row))*64 + (col-128)] = val;
    }
  }
  __syncthreads();

  // xd[which*64+pos] = 0.5*sum(z^2)
  if (t < 128){
    int pos = t & 63, wh = t >> 6;
    float s = 0.f;
    #pragma unroll 8
    for (int c=0;c<64;++c){
      float z = zq[pos*129 + wh*64 + c];
      s += z*z;
    }
    xd_s[t] = 0.5f*s;
  }
  __syncthreads();

  // 4096 dots: exp(w.z - xd)/sqrt(M)
  const int m = t & 31;
  #pragma unroll
  for (int it=0; it<16; ++it){
    int qi = it*8 + (t>>5);          // 0..127
    int pos = qi & 63, wh = qi >> 6;
    const float* zr = &zq[pos*129 + wh*64];
    const float* wr = &wperf_s[m*65];
    float wtx = 0.f;
    #pragma unroll 8
    for (int c=0;c<64;++c) wtx += zr[c]*wr[c];
    float outv = expf(wtx - xd_s[qi]) * 0.17677669529663687f;
    float* dst = wh ? qp : kp;
    dst[((size_t)(m0+pos))*32 + m] = outv;
  }
}

// ---------------- kpsum[b][m] = sum_t kp[b][t][m]
__global__ __launch_bounds__(256) void k_kpsum(
    const float* __restrict__ kp, float* __restrict__ kpsum)
{
  const int b = blockIdx.x;
  const int m = threadIdx.x & 31, g = threadIdx.x >> 5;
  __shared__ float part[8][32];
  float s = 0.f;
  for (int tt = g; tt < TT; tt += 8)
    s += kp[((size_t)b*TT + tt)*MM + m];
  part[g][m] = s;
  __syncthreads();
  if (threadIdx.x < 32){
    float a = 0.f;
    #pragma unroll
    for (int g2=0;g2<8;++g2) a += part[g2][threadIdx.x];
    kpsum[b*MM + threadIdx.x] = a;
  }
}

// ---------------- kptv partials
__global__ __launch_bounds__(256) void k_kptv(
    const float* __restrict__ v_g, const float* __restrict__ kp,
    float* __restrict__ part)
{
  const int b = blockIdx.y, g = blockIdx.x;
  const int n = threadIdx.x & 63, mg = threadIdx.x >> 6;
  float acc[8] = {0,0,0,0,0,0,0,0};
  for (int tt = g*196; tt < (g+1)*196; ++tt){
    float vv = v_g[((size_t)b*TT + tt)*64 + n];
    const float4* kp4 = (const float4*)(kp + ((size_t)b*TT + tt)*MM + mg*8);
    float4 a0 = kp4[0], a1 = kp4[1];
    acc[0] += vv*a0.x; acc[1] += vv*a0.y; acc[2] += vv*a0.z; acc[3] += vv*a0.w;
    acc[4] += vv*a1.x; acc[5] += vv*a1.y; acc[6] += vv*a1.z; acc[7] += vv*a1.w;
  }
  #pragma unroll
  for (int j=0;j<8;++j)
    part[(((size_t)g*BB + b)*64 + n)*MM + mg*8 + j] = acc[j];
}

__global__ __launch_bounds__(256) void k_kptv_red(
    const float* __restrict__ part, float* __restrict__ kptv)
{
  const int idx = blockIdx.x*256 + threadIdx.x;
  float a = 0.f;
  #pragma unroll
  for (int g=0; g<16; ++g) a += part[(size_t)g*65536 + idx];
  kptv[idx] = a;
}

// ---------------- attention out + proj + residuals -> xo (d_out); 32 pos/block
__global__ __launch_bounds__(256) void k_attn(
    const float* __restrict__ v_g, const float* __restrict__ qp,
    const float* __restrict__ kpsum, const float* __restrict__ kptv,
    const float* __restrict__ projw, const float* __restrict__ projb,
    const float* __restrict__ convX, float* __restrict__ xo)
{
  __shared__ float pw[64*65];
  __shared__ float ktv[64*33];
  __shared__ float ks[32];
  __shared__ float tsh[4][64];
  const int t = threadIdx.x, n = t & 63, p = t >> 6;
  const int b = blockIdx.y;
  for (int idx=t; idx<4096; idx+=256) pw[(idx>>6)*65 + (idx&63)] = projw[idx];
  for (int idx=t; idx<2048; idx+=256) ktv[(idx>>5)*33 + (idx&31)] = kptv[b*2048 + idx];
  if (t < 32) ks[t] = kpsum[b*MM + t];
  __syncthreads();
  const float pb = projb[n];
  for (int sp=0; sp<8; ++sp){
    const int s = blockIdx.x*32 + sp*4 + p;
    const float* qpp = qp + ((size_t)b*TT + s)*MM;
    float D = 0.f, num = 0.f;
    #pragma unroll 8
    for (int m=0;m<32;++m){
      float q = qpp[m];
      D   += q*ks[m];
      num += q*ktv[n*33+m];
    }
    tsh[p][n] = num / (D + 1e-8f);
    __syncthreads();
    float acc = pb;
    #pragma unroll 8
    for (int j=0;j<64;++j) acc += tsh[p][j]*pw[n*65+j];
    const size_t off = ((size_t)b*TT + s)*64 + n;
    xo[off] = v_g[off] + acc + convX[off];
    __syncthreads();
  }
}

// ---------------- final MLP, in place on d_out; 32 pos/block
__global__ __launch_bounds__(256) void k_mlp(
    const float* __restrict__ ln2_g, const float* __restrict__ ln2_b,
    const float* __restrict__ w1, const float* __restrict__ b1,
    const float* __restrict__ w2, const float* __restrict__ b2,
    float* __restrict__ out)
{
  __shared__ float w1s[64*65], w2s[64*65];
  __shared__ float lnsh[4][64], h1sh[4][64];
  const int t = threadIdx.x, n = t & 63, p = t >> 6;
  const int b = blockIdx.y;
  for (int idx=t; idx<4096; idx+=256){
    int r = idx >> 6, c = idx & 63;
    w1s[r*65+c] = w1[idx];
    w2s[r*65+c] = w2[idx];
  }
  __syncthreads();
  const float g2 = ln2_g[n], bb2 = ln2_b[n];
  const float bb1 = b1[n], bbo = b2[n];
  for (int sp=0; sp<8; ++sp){
    const int s = blockIdx.x*32 + sp*4 + p;
    const size_t off = ((size_t)b*TT + s)*64;
    const float xv = out[off + n];
    float s1 = xv, s2 = xv*xv;
    #pragma unroll
    for (int o=32;o;o>>=1){
      s1 += __shfl_xor(s1, o, 64);
      s2 += __shfl_xor(s2, o, 64);
    }
    float mu = s1*(1.f/64.f);
    float rs = rsqrtf(s2*(1.f/64.f) - mu*mu + 1e-5f);
    lnsh[p][n] = (xv - mu)*rs*g2 + bb2;
    __syncthreads();
    float acc = bb1;
    #pragma unroll 8
    for (int c=0;c<64;++c) acc += lnsh[p][c]*w1s[n*65+c];
    h1sh[p][n] = geluf(acc);
    __syncthreads();
    float acc2 = bbo;
    #pragma unroll 8
    for (int c=0;c<64;++c) acc2 += h1sh[p][c]*w2s[n*65+c];
    out[off + n] = xv + acc2;
    __syncthreads();
  }
}

extern "C" void kernel_launch(void* const* d_in, const int* in_sizes, int n_in,
                              void* d_out, int out_size, void* d_ws, size_t ws_size,
                              hipStream_t stream)
{
  const float* x      = (const float*)d_in[0];
  const float* prm_w  = (const float*)d_in[1];
  const float* prm_b  = (const float*)d_in[2];
  const float* pcm_w1 = (const float*)d_in[3];
  const float* pcm_b1 = (const float*)d_in[4];
  const float* pcm_w2 = (const float*)d_in[5];
  const float* pcm_b2 = (const float*)d_in[6];
  const float* bn_g   = (const float*)d_in[7];
  const float* bn_b   = (const float*)d_in[8];
  const float* bn_mean= (const float*)d_in[9];
  const float* bn_var = (const float*)d_in[10];
  const float* pcm_w3 = (const float*)d_in[11];
  const float* pcm_b3 = (const float*)d_in[12];
  const float* ln1_g  = (const float*)d_in[13];
  const float* ln1_b  = (const float*)d_in[14];
  const float* kqv_w  = (const float*)d_in[15];
  const float* kqv_b  = (const float*)d_in[16];
  const float* w_perf = (const float*)d_in[17];
  const float* proj_w = (const float*)d_in[18];
  const float* proj_b = (const float*)d_in[19];
  const float* ln2_g  = (const float*)d_in[20];
  const float* ln2_b  = (const float*)d_in[21];
  const float* mlp_w1 = (const float*)d_in[22];
  const float* mlp_b1 = (const float*)d_in[23];
  const float* mlp_w2 = (const float*)d_in[24];
  const float* mlp_b2 = (const float*)d_in[25];

  float* ws = (float*)d_ws;
  float* c1    = ws + OFF_C1;
  float* c2    = ws + OFF_C2;
  float* convX = ws + OFF_CONVX;
  __hip_bfloat16* xn = (__hip_bfloat16*)(ws + OFF_XN);
  float* v_g   = ws + OFF_V;
  float* kp    = ws + OFF_KP;
  float* qp    = ws + OFF_QP;
  float* part  = ws + OFF_PART;
  float* kptv  = ws + OFF_KPTV;
  float* kpsum = ws + OFF_KPSUM;
  float* wt3   = ws + OFF_WT3;
  float* wpt   = ws + OFF_WPT;
  float* wc2   = ws + OFF_WC2;
  __hip_bfloat16* wkb = (__hip_bfloat16*)(ws + OFF_WKB);
  float* out   = (float*)d_out;

  k_wtrans<<<dim3(627), 256, 0, stream>>>(pcm_w3, prm_w, pcm_w2, kqv_w,
                                          wt3, wpt, wc2, wkb);
  // CNN stem
  k_conv1<<<dim3(56,BB), 256, 0, stream>>>(x, pcm_w1, pcm_b1, c1);
  k_conv2<<<dim3(49,BB), 256, 0, stream>>>(c1, wc2, pcm_b2, bn_g, bn_b,
                                           bn_mean, bn_var, c2);
  k_conv3<<<dim3(49,BB), 256, 0, stream>>>(c2, wt3, pcm_b3, convX);
  // PRM + LN -> xn (bf16)
  k_prm_ln<<<dim3(224,BB), 256, 0, stream>>>(x, wpt, prm_b, ln1_g, ln1_b, xn);
  // KQV GEMM (MFMA) + Performer features
  k_kqv_perf<<<dim3(1568), 256, 0, stream>>>(xn, wkb, kqv_b, w_perf, v_g, kp, qp);
  // Performer reductions
  k_kpsum<<<dim3(BB), 256, 0, stream>>>(kp, kpsum);
  k_kptv<<<dim3(16,BB), 256, 0, stream>>>(v_g, kp, part);
  k_kptv_red<<<dim3(256), 256, 0, stream>>>(part, kptv);
  // attention output + residuals -> xo in d_out
  k_attn<<<dim3(98,BB), 256, 0, stream>>>(v_g, qp, kpsum, kptv, proj_w, proj_b,
                                          convX, out);
  // final MLP in place
  k_mlp<<<dim3(98,BB), 256, 0, stream>>>(ln2_g, ln2_b, mlp_w1, mlp_b1,
                                         mlp_w2, mlp_b2, out);
}